// Round 1
// baseline (172.323 us; speedup 1.0000x reference)
//
#include <hip/hip_runtime.h>

// Problem constants (from reference): S = 1024*1024, ranks [1,3,3,3,3,1].
#define SDIM (1024 * 1024)
#define GROUPS (SDIM / 4)      // each thread handles 4 consecutive s values
#define K1_BLOCKS 1024
#define K1_THREADS 256
#define NACC 30                // 3 (V0) + 9*3 (V1..V3)
#define PART_STRIDE 32         // padded per-block partial vector

__device__ __forceinline__ float wave_reduce(float v) {
    #pragma unroll
    for (int off = 32; off > 0; off >>= 1)
        v += __shfl_down(v, off, 64);
    return v;
}

// K1: compute per-block partial sums of the 30 reductions
//   V0[q]      = sum_s z[s] * TT0[s*3+q]
//   Vk[r][q]   = sum_s z[s] * TTk[r*3S + s*3 + q],  k=1..3
__global__ __launch_bounds__(K1_THREADS) void ftt_k1(
    const float* __restrict__ z,
    const float* __restrict__ t0,
    const float* __restrict__ t1,
    const float* __restrict__ t2,
    const float* __restrict__ t3,
    float* __restrict__ partials)
{
    float acc[NACC];
    #pragma unroll
    for (int i = 0; i < NACC; ++i) acc[i] = 0.0f;

    const int g = blockIdx.x * K1_THREADS + threadIdx.x;   // group index, exactly covers GROUPS

    // z: 4 consecutive values
    const float4 z4 = reinterpret_cast<const float4*>(z)[g];
    const float zz[4] = {z4.x, z4.y, z4.z, z4.w};

    // TT0 (r-dim = 1): 12 contiguous floats at 12*g
    {
        const float4* p = reinterpret_cast<const float4*>(t0 + 12 * g);
        const float4 c0 = p[0], c1 = p[1], c2 = p[2];
        const float tt[12] = {c0.x, c0.y, c0.z, c0.w,
                              c1.x, c1.y, c1.z, c1.w,
                              c2.x, c2.y, c2.z, c2.w};
        #pragma unroll
        for (int j = 0; j < 4; ++j)
            #pragma unroll
            for (int q = 0; q < 3; ++q)
                acc[q] += zz[j] * tt[j * 3 + q];
    }

    // TT1..TT3: three r-planes each, 12 contiguous floats per plane at r*3S + 12*g
    const float* __restrict__ Ts[3] = {t1, t2, t3};
    #pragma unroll
    for (int k = 0; k < 3; ++k) {
        #pragma unroll
        for (int r = 0; r < 3; ++r) {
            const float4* p = reinterpret_cast<const float4*>(Ts[k] + r * 3 * SDIM + 12 * g);
            const float4 c0 = p[0], c1 = p[1], c2 = p[2];
            const float tt[12] = {c0.x, c0.y, c0.z, c0.w,
                                  c1.x, c1.y, c1.z, c1.w,
                                  c2.x, c2.y, c2.z, c2.w};
            #pragma unroll
            for (int j = 0; j < 4; ++j)
                #pragma unroll
                for (int q = 0; q < 3; ++q)
                    acc[3 + k * 9 + r * 3 + q] += zz[j] * tt[j * 3 + q];
        }
    }

    // wave (64-lane) shuffle reduction for each accumulator
    #pragma unroll
    for (int i = 0; i < NACC; ++i)
        acc[i] = wave_reduce(acc[i]);

    // cross-wave reduction through LDS (4 waves per block)
    __shared__ float red[4][NACC];
    const int lane = threadIdx.x & 63;
    const int wave = threadIdx.x >> 6;
    if (lane == 0) {
        #pragma unroll
        for (int i = 0; i < NACC; ++i) red[wave][i] = acc[i];
    }
    __syncthreads();
    if (threadIdx.x < NACC) {
        const float s = red[0][threadIdx.x] + red[1][threadIdx.x] +
                        red[2][threadIdx.x] + red[3][threadIdx.x];
        partials[blockIdx.x * PART_STRIDE + threadIdx.x] = s;
    }
}

// K2: reduce 1024 partial vectors -> 30 sums, then compute f = V0 @ V1 @ V2 @ V3 (3 floats)
__global__ __launch_bounds__(256) void ftt_k2(
    const float* __restrict__ partials,
    float* __restrict__ fvec)
{
    __shared__ float part[8][32];
    const int c = threadIdx.x & 31;   // component 0..31 (30 used)
    const int grp = threadIdx.x >> 5; // 0..7, each sums 128 blocks
    float s = 0.0f;
    const int b0 = grp * (K1_BLOCKS / 8);
    for (int b = b0; b < b0 + (K1_BLOCKS / 8); ++b)
        s += partials[b * PART_STRIDE + c];
    part[grp][c] = s;
    __syncthreads();

    if (threadIdx.x == 0) {
        float sum[NACC];
        #pragma unroll
        for (int i = 0; i < NACC; ++i) {
            float t = 0.0f;
            #pragma unroll
            for (int gg = 0; gg < 8; ++gg) t += part[gg][i];
            sum[i] = t;
        }
        // f = V0 (1x3); then f = f @ Vk for k=1..3
        float f0 = sum[0], f1 = sum[1], f2 = sum[2];
        #pragma unroll
        for (int k = 0; k < 3; ++k) {
            const float* V = &sum[3 + k * 9];   // V[r*3+q]
            const float n0 = f0 * V[0] + f1 * V[3] + f2 * V[6];
            const float n1 = f0 * V[1] + f1 * V[4] + f2 * V[7];
            const float n2 = f0 * V[2] + f1 * V[5] + f2 * V[8];
            f0 = n0; f1 = n1; f2 = n2;
        }
        fvec[0] = f0; fvec[1] = f1; fvec[2] = f2;
    }
}

// K3: out[s] = f0*TT4[0,s] + f1*TT4[1,s] + f2*TT4[2,s]   (TT4 is (3,S,1) -> plane stride S)
__global__ __launch_bounds__(256) void ftt_k3(
    const float* __restrict__ t4,
    const float* __restrict__ fvec,
    float* __restrict__ out)
{
    const int i = blockIdx.x * blockDim.x + threadIdx.x;   // float4 index, exactly S/4 total
    const float f0 = fvec[0], f1 = fvec[1], f2 = fvec[2];
    const float4 a = reinterpret_cast<const float4*>(t4)[i];
    const float4 b = reinterpret_cast<const float4*>(t4 + SDIM)[i];
    const float4 c = reinterpret_cast<const float4*>(t4 + 2 * SDIM)[i];
    float4 o;
    o.x = f0 * a.x + f1 * b.x + f2 * c.x;
    o.y = f0 * a.y + f1 * b.y + f2 * c.y;
    o.z = f0 * a.z + f1 * b.z + f2 * c.z;
    o.w = f0 * a.w + f1 * b.w + f2 * c.w;
    reinterpret_cast<float4*>(out)[i] = o;
}

extern "C" void kernel_launch(void* const* d_in, const int* in_sizes, int n_in,
                              void* d_out, int out_size, void* d_ws, size_t ws_size,
                              hipStream_t stream)
{
    const float* z  = (const float*)d_in[0];
    const float* t0 = (const float*)d_in[1];
    const float* t1 = (const float*)d_in[2];
    const float* t2 = (const float*)d_in[3];
    const float* t3 = (const float*)d_in[4];
    const float* t4 = (const float*)d_in[5];
    float* out = (float*)d_out;

    float* partials = (float*)d_ws;                       // K1_BLOCKS * PART_STRIDE floats
    float* fvec     = partials + K1_BLOCKS * PART_STRIDE; // 3 floats

    ftt_k1<<<K1_BLOCKS, K1_THREADS, 0, stream>>>(z, t0, t1, t2, t3, partials);
    ftt_k2<<<1, 256, 0, stream>>>(partials, fvec);
    ftt_k3<<<SDIM / 4 / 256, 256, 0, stream>>>(t4, fvec, out);
}

// Round 2
// 172.267 us; speedup vs baseline: 1.0003x; 1.0003x over previous
//
#include <hip/hip_runtime.h>

// S = 1024*1024, ranks [1,3,3,3,3,1].
#define SDIM (1024 * 1024)
#define GROUPS (SDIM / 4)       // float4 groups of s
#define CHUNKS 1024             // chunks per plane; CHUNKS*256 == GROUPS
#define NPLANE 10               // TT0 (1 plane) + TT1..TT3 (3 planes each)

// K1: grid (CHUNKS, NPLANE). Each block computes a partial 3-vector:
//   part[plane][chunk][q] = sum_{s in chunk} z[s] * plane[s*3 + q]
__global__ __launch_bounds__(256) void ftt_k1(
    const float* __restrict__ z,
    const float* __restrict__ t0,
    const float* __restrict__ t1,
    const float* __restrict__ t2,
    const float* __restrict__ t3,
    float* __restrict__ partials)   // [NPLANE][CHUNKS][4]
{
    const int plane = blockIdx.y;
    const int g = blockIdx.x * 256 + threadIdx.x;   // group index in [0, GROUPS)

    const float* base;
    if (plane == 0) {
        base = t0;
    } else {
        const int pk = plane - 1;
        const int k = pk / 3;                        // wave-uniform
        const float* tk = (k == 0) ? t1 : (k == 1) ? t2 : t3;
        base = tk + (pk % 3) * (3 * SDIM);
    }

    const float4 z4 = reinterpret_cast<const float4*>(z)[g];
    const float4* p = reinterpret_cast<const float4*>(base + 12 * g);
    const float4 c0 = p[0], c1 = p[1], c2 = p[2];

    // acc[q] = sum_j z_j * tt[3j+q]; tt flat = c0.xyzw c1.xyzw c2.xyzw
    float a0 = z4.x * c0.x + z4.y * c0.w + z4.z * c1.z + z4.w * c2.y;
    float a1 = z4.x * c0.y + z4.y * c1.x + z4.z * c1.w + z4.w * c2.z;
    float a2 = z4.x * c0.z + z4.y * c1.y + z4.z * c2.x + z4.w * c2.w;

    // wave (64) shuffle reduction
    #pragma unroll
    for (int off = 32; off > 0; off >>= 1) {
        a0 += __shfl_down(a0, off, 64);
        a1 += __shfl_down(a1, off, 64);
        a2 += __shfl_down(a2, off, 64);
    }

    __shared__ float red[4][3];
    const int lane = threadIdx.x & 63;
    const int wave = threadIdx.x >> 6;
    if (lane == 0) { red[wave][0] = a0; red[wave][1] = a1; red[wave][2] = a2; }
    __syncthreads();
    if (threadIdx.x < 3) {
        const int c = threadIdx.x;
        const float s = red[0][c] + red[1][c] + red[2][c] + red[3][c];
        partials[(plane * CHUNKS + blockIdx.x) * 4 + c] = s;
    }
}

// K2: reduce [NPLANE][CHUNKS] partial triples -> 30 sums -> f = V0@V1@V2@V3 (3 floats)
__global__ __launch_bounds__(256) void ftt_k2(
    const float* __restrict__ partials,
    float* __restrict__ fvec)
{
    __shared__ float red[NPLANE * 3][8];
    const int job = threadIdx.x >> 3;   // 0..31 (30 used): job = plane*3 + c
    const int sub = threadIdx.x & 7;    // 8 threads per job, 128 chunks each
    if (job < NPLANE * 3) {
        const int plane = job / 3, c = job % 3;
        float s = 0.0f;
        const int b0 = sub * (CHUNKS / 8);
        #pragma unroll 4
        for (int b = b0; b < b0 + (CHUNKS / 8); ++b)
            s += partials[(plane * CHUNKS + b) * 4 + c];
        red[job][sub] = s;
    }
    __syncthreads();

    if (threadIdx.x == 0) {
        float sum[NPLANE * 3];
        #pragma unroll
        for (int i = 0; i < NPLANE * 3; ++i) {
            float t = 0.0f;
            #pragma unroll
            for (int g = 0; g < 8; ++g) t += red[i][g];
            sum[i] = t;
        }
        float f0 = sum[0], f1 = sum[1], f2 = sum[2];
        #pragma unroll
        for (int k = 0; k < 3; ++k) {
            const float* V = &sum[3 + k * 9];   // V[r*3+q], r = plane within core
            const float n0 = f0 * V[0] + f1 * V[3] + f2 * V[6];
            const float n1 = f0 * V[1] + f1 * V[4] + f2 * V[7];
            const float n2 = f0 * V[2] + f1 * V[5] + f2 * V[8];
            f0 = n0; f1 = n1; f2 = n2;
        }
        fvec[0] = f0; fvec[1] = f1; fvec[2] = f2;
    }
}

// K3: out[s] = f0*TT4[0,s] + f1*TT4[1,s] + f2*TT4[2,s]   (TT4 is (3,S,1))
__global__ __launch_bounds__(256) void ftt_k3(
    const float* __restrict__ t4,
    const float* __restrict__ fvec,
    float* __restrict__ out)
{
    const int i = blockIdx.x * blockDim.x + threadIdx.x;   // float4 index
    const float f0 = fvec[0], f1 = fvec[1], f2 = fvec[2];
    const float4 a = reinterpret_cast<const float4*>(t4)[i];
    const float4 b = reinterpret_cast<const float4*>(t4 + SDIM)[i];
    const float4 c = reinterpret_cast<const float4*>(t4 + 2 * SDIM)[i];
    float4 o;
    o.x = f0 * a.x + f1 * b.x + f2 * c.x;
    o.y = f0 * a.y + f1 * b.y + f2 * c.y;
    o.z = f0 * a.z + f1 * b.z + f2 * c.z;
    o.w = f0 * a.w + f1 * b.w + f2 * c.w;
    reinterpret_cast<float4*>(out)[i] = o;
}

extern "C" void kernel_launch(void* const* d_in, const int* in_sizes, int n_in,
                              void* d_out, int out_size, void* d_ws, size_t ws_size,
                              hipStream_t stream)
{
    const float* z  = (const float*)d_in[0];
    const float* t0 = (const float*)d_in[1];
    const float* t1 = (const float*)d_in[2];
    const float* t2 = (const float*)d_in[3];
    const float* t3 = (const float*)d_in[4];
    const float* t4 = (const float*)d_in[5];
    float* out = (float*)d_out;

    float* partials = (float*)d_ws;                      // NPLANE*CHUNKS*4 floats = 160 KB
    float* fvec     = partials + NPLANE * CHUNKS * 4;    // 3 floats

    ftt_k1<<<dim3(CHUNKS, NPLANE), 256, 0, stream>>>(z, t0, t1, t2, t3, partials);
    ftt_k2<<<1, 256, 0, stream>>>(partials, fvec);
    ftt_k3<<<SDIM / 4 / 256, 256, 0, stream>>>(t4, fvec, out);
}

// Round 3
// 167.623 us; speedup vs baseline: 1.0280x; 1.0277x over previous
//
#include <hip/hip_runtime.h>

// S = 1024*1024, ranks [1,3,3,3,3,1].
#define SDIM (1024 * 1024)
#define GROUPS (SDIM / 4)            // float4 groups of s (262144)
#define GPT 4                        // float4-groups per thread in K1
#define CHUNKS (GROUPS / (256 * GPT))// 256 chunks per plane
#define NPLANE 10                    // TT0 (1 plane) + TT1..TT3 (3 planes each)

// K1: grid (CHUNKS, NPLANE). Each block computes a partial 3-vector:
//   part[plane][chunk][q] = sum_{s in chunk} z[s] * plane[s*3 + q]
// Each thread accumulates GPT float4-groups before the cross-lane reduction,
// amortizing the 18-shuffle tail (round-2 bottleneck: tail ~= load time).
__global__ __launch_bounds__(256) void ftt_k1(
    const float* __restrict__ z,
    const float* __restrict__ t0,
    const float* __restrict__ t1,
    const float* __restrict__ t2,
    const float* __restrict__ t3,
    float* __restrict__ partials)   // [NPLANE][CHUNKS][4]
{
    const int plane = blockIdx.y;

    const float* base;
    if (plane == 0) {
        base = t0;
    } else {
        const int pk = plane - 1;
        const int k = pk / 3;                        // wave-uniform
        const float* tk = (k == 0) ? t1 : (k == 1) ? t2 : t3;
        base = tk + (pk % 3) * (3 * SDIM);
    }

    const int g0 = blockIdx.x * (256 * GPT) + threadIdx.x;
    float a0 = 0.0f, a1 = 0.0f, a2 = 0.0f;

    #pragma unroll
    for (int it = 0; it < GPT; ++it) {
        const int g = g0 + it * 256;
        const float4 z4 = reinterpret_cast<const float4*>(z)[g];
        const float4* p = reinterpret_cast<const float4*>(base + 12 * g);
        const float4 c0 = p[0], c1 = p[1], c2 = p[2];
        // acc[q] += sum_j z_j * tt[3j+q]; tt flat = c0.xyzw c1.xyzw c2.xyzw
        a0 += z4.x * c0.x + z4.y * c0.w + z4.z * c1.z + z4.w * c2.y;
        a1 += z4.x * c0.y + z4.y * c1.x + z4.z * c1.w + z4.w * c2.z;
        a2 += z4.x * c0.z + z4.y * c1.y + z4.z * c2.x + z4.w * c2.w;
    }

    // wave (64) shuffle reduction
    #pragma unroll
    for (int off = 32; off > 0; off >>= 1) {
        a0 += __shfl_down(a0, off, 64);
        a1 += __shfl_down(a1, off, 64);
        a2 += __shfl_down(a2, off, 64);
    }

    __shared__ float red[4][3];
    const int lane = threadIdx.x & 63;
    const int wave = threadIdx.x >> 6;
    if (lane == 0) { red[wave][0] = a0; red[wave][1] = a1; red[wave][2] = a2; }
    __syncthreads();
    if (threadIdx.x < 3) {
        const int c = threadIdx.x;
        const float s = red[0][c] + red[1][c] + red[2][c] + red[3][c];
        partials[(plane * CHUNKS + blockIdx.x) * 4 + c] = s;
    }
}

// K2: reduce [NPLANE][CHUNKS] partial triples -> 30 sums -> f = V0@V1@V2@V3 (3 floats)
__global__ __launch_bounds__(256) void ftt_k2(
    const float* __restrict__ partials,
    float* __restrict__ fvec)
{
    __shared__ float red[NPLANE * 3][8];
    const int job = threadIdx.x >> 3;   // 0..31 (30 used): job = plane*3 + c
    const int sub = threadIdx.x & 7;    // 8 threads per job, CHUNKS/8 chunks each
    if (job < NPLANE * 3) {
        const int plane = job / 3, c = job % 3;
        float s = 0.0f;
        const int b0 = sub * (CHUNKS / 8);
        #pragma unroll 4
        for (int b = b0; b < b0 + (CHUNKS / 8); ++b)
            s += partials[(plane * CHUNKS + b) * 4 + c];
        red[job][sub] = s;
    }
    __syncthreads();

    if (threadIdx.x == 0) {
        float sum[NPLANE * 3];
        #pragma unroll
        for (int i = 0; i < NPLANE * 3; ++i) {
            float t = 0.0f;
            #pragma unroll
            for (int g = 0; g < 8; ++g) t += red[i][g];
            sum[i] = t;
        }
        float f0 = sum[0], f1 = sum[1], f2 = sum[2];
        #pragma unroll
        for (int k = 0; k < 3; ++k) {
            const float* V = &sum[3 + k * 9];   // V[r*3+q]
            const float n0 = f0 * V[0] + f1 * V[3] + f2 * V[6];
            const float n1 = f0 * V[1] + f1 * V[4] + f2 * V[7];
            const float n2 = f0 * V[2] + f1 * V[5] + f2 * V[8];
            f0 = n0; f1 = n1; f2 = n2;
        }
        fvec[0] = f0; fvec[1] = f1; fvec[2] = f2;
    }
}

// K3: out[s] = f0*TT4[0,s] + f1*TT4[1,s] + f2*TT4[2,s]   (TT4 is (3,S,1))
__global__ __launch_bounds__(256) void ftt_k3(
    const float* __restrict__ t4,
    const float* __restrict__ fvec,
    float* __restrict__ out)
{
    const int i = blockIdx.x * blockDim.x + threadIdx.x;   // float4 index
    const float f0 = fvec[0], f1 = fvec[1], f2 = fvec[2];
    const float4 a = reinterpret_cast<const float4*>(t4)[i];
    const float4 b = reinterpret_cast<const float4*>(t4 + SDIM)[i];
    const float4 c = reinterpret_cast<const float4*>(t4 + 2 * SDIM)[i];
    float4 o;
    o.x = f0 * a.x + f1 * b.x + f2 * c.x;
    o.y = f0 * a.y + f1 * b.y + f2 * c.y;
    o.z = f0 * a.z + f1 * b.z + f2 * c.z;
    o.w = f0 * a.w + f1 * b.w + f2 * c.w;
    reinterpret_cast<float4*>(out)[i] = o;
}

extern "C" void kernel_launch(void* const* d_in, const int* in_sizes, int n_in,
                              void* d_out, int out_size, void* d_ws, size_t ws_size,
                              hipStream_t stream)
{
    const float* z  = (const float*)d_in[0];
    const float* t0 = (const float*)d_in[1];
    const float* t1 = (const float*)d_in[2];
    const float* t2 = (const float*)d_in[3];
    const float* t3 = (const float*)d_in[4];
    const float* t4 = (const float*)d_in[5];
    float* out = (float*)d_out;

    float* partials = (float*)d_ws;                      // NPLANE*CHUNKS*4 floats
    float* fvec     = partials + NPLANE * CHUNKS * 4;    // 3 floats

    ftt_k1<<<dim3(CHUNKS, NPLANE), 256, 0, stream>>>(z, t0, t1, t2, t3, partials);
    ftt_k2<<<1, 256, 0, stream>>>(partials, fvec);
    ftt_k3<<<SDIM / 4 / 256, 256, 0, stream>>>(t4, fvec, out);
}